// Round 8
// baseline (167.620 us; speedup 1.0000x reference)
//
#include <hip/hip_runtime.h>

#define N_NODES 50000
#define N_EDGES 640000
#define D 128          // D_IN == D_OUT
#define NB 8           // num bases
#define PAD 32         // bucket slots per dst (mean deg 12.8; overflow -> side list)
#define NSTRIP 3125    // 50000 / 16 row-strips
#define NBLK_G 3125    // gather blocks: 16 nodes each

// Role split: 256 bucket blocks (proven optimum; contention-bound) + 768 gemm
// blocks = 1024 blocks, 4/CU resident. Bucket uses the simple R1 loop (4-wide
// batching measured neutral; more threads measured worse).
#define BUCKET_B 256
#define GEMM_B   768

typedef _Float16 half_t;
typedef __attribute__((ext_vector_type(8))) _Float16 half8;
typedef __attribute__((ext_vector_type(4))) float f32x4;

// ---- k0: zero counters + build Wt/Rt (fp16, transposed [n][k]) + zero y pad row ----
__global__ __launch_bounds__(256)
void init_kernel(const float* __restrict__ bases,
                 const float* __restrict__ comp,
                 const float* __restrict__ root,
                 half_t* __restrict__ Wt,
                 half_t* __restrict__ Rt,
                 half_t* __restrict__ y,
                 int* __restrict__ cnt,
                 int* __restrict__ novf) {
    int i = blockIdx.x * 256 + threadIdx.x;
    if (i == 0) *novf = 0;
    if (i < N_NODES) cnt[i] = 0;
    if (i < D) y[(size_t)N_NODES * D + i] = (half_t)0.f;   // zero row for gather padding
    if (i < D * D) {
        int ii = i >> 7, o = i & 127;
        float acc = 0.f;
#pragma unroll
        for (int b = 0; b < NB; ++b)
            acc += comp[b] * bases[((size_t)b * D + ii) * D + o];
        Wt[o * D + ii] = (half_t)acc;
        Rt[o * D + ii] = (half_t)root[i];
    }
}

// ---- k1 (fused): bucket role || gemm role (W-only: y = x@W, no out write) ----
__global__ __launch_bounds__(256, 4)
void fused_kernel(const float* __restrict__ x,
                  const half_t* __restrict__ Wt,   // [n][k]
                  const int* __restrict__ eidx,
                  half_t* __restrict__ y,
                  int* __restrict__ cnt,
                  int* __restrict__ bucket,
                  int* __restrict__ ovf,
                  int* __restrict__ novf) {
    const int tid = threadIdx.x;

    if (blockIdx.x < BUCKET_B) {
        // ---------------- bucket role ----------------
        int t = blockIdx.x * 256 + tid;
        for (int e = t; e < N_EDGES; e += BUCKET_B * 256) {
            int src = eidx[e];
            int dst = eidx[N_EDGES + e];
            int pos = atomicAdd(&cnt[dst], 1);
            if (pos < PAD) {
                bucket[(size_t)dst * PAD + pos] = src;
            } else {            // P ~ 1e-7; capacity == E, never drops
                int k = atomicAdd(novf, 1);
                ovf[2 * k]     = src;
                ovf[2 * k + 1] = dst;
            }
        }
        return;
    }

    // ---------------- gemm role: y = x@W only ----------------
    const int gb   = blockIdx.x - BUCKET_B;  // 0 .. GEMM_B-1
    const int wave = tid >> 6;
    const int lane = tid & 63;
    const int m    = lane & 15;
    const int quad = lane >> 4;
    const int q    = wave;                   // col quarter: nt = 2q, 2q+1

    // B fragments, loaded ONCE: B[k][n], n = lane&15, k = quad*8 + j
    half8 bw[2][4];
#pragma unroll
    for (int t = 0; t < 2; ++t) {
        const half_t* wp = Wt + ((2 * q + t) * 16 + m) * D + quad * 8;
#pragma unroll
        for (int kk = 0; kk < 4; ++kk)
            bw[t][kk] = *(const half8*)(wp + kk * 32);
    }

    const float4* x4 = (const float4*)x;
    for (int s = gb; s < NSTRIP; s += GEMM_B) {
        // A fragment: A[m][k], row = s*16 + m, k = quad*8 + j
        size_t ab = (size_t)(s * 16 + m) * 32 + quad * 2;
        half8 a[4];
#pragma unroll
        for (int kk = 0; kk < 4; ++kk) {
            float4 v0 = x4[ab + kk * 8];
            float4 v1 = x4[ab + kk * 8 + 1];
            half8 h;
            h[0] = (half_t)v0.x; h[1] = (half_t)v0.y; h[2] = (half_t)v0.z; h[3] = (half_t)v0.w;
            h[4] = (half_t)v1.x; h[5] = (half_t)v1.y; h[6] = (half_t)v1.z; h[7] = (half_t)v1.w;
            a[kk] = h;
        }

        f32x4 accW[2];
#pragma unroll
        for (int t = 0; t < 2; ++t) accW[t] = (f32x4){0.f, 0.f, 0.f, 0.f};
#pragma unroll
        for (int t = 0; t < 2; ++t)
#pragma unroll
            for (int kk = 0; kk < 4; ++kk)
                accW[t] = __builtin_amdgcn_mfma_f32_16x16x32_f16(a[kk], bw[t][kk], accW[t], 0, 0, 0);

        // C/D layout: col = lane&15, row = quad*4 + reg
#pragma unroll
        for (int t = 0; t < 2; ++t) {
            int col = (2 * q + t) * 16 + m;
#pragma unroll
            for (int r = 0; r < 4; ++r)
                y[(size_t)(s * 16 + quad * 4 + r) * D + col] = (half_t)accW[t][r];
        }
    }
}

// ---- k2: gather + root, 16 nodes per block ----
// Phase R: per-block root MFMA (x_tile @ Rt + bias) -> ldsO. Uniform work, one
//          barrier; x and Rt are L2/L3-hot after fused.
// Phase G: each wave handles 4 nodes. Fixed slot split (group quad owns slots
//          quad*8..quad*8+7) lets bucket-row loads issue IN PARALLEL with the
//          cnt load (mask-select after). v-loads padded to the zeroed y row.
//          shfl_xor(16,32) combine; quad==0 writes out = gathered + root
//          in ONE coalesced pass (no RMW).
__global__ __launch_bounds__(256)
void gather_kernel(const float* __restrict__ x,
                   const half_t* __restrict__ Rt,   // [n][k]
                   const float* __restrict__ bias,
                   const int* __restrict__ cnt,
                   const int* __restrict__ bucket,
                   const half_t* __restrict__ y,
                   const int* __restrict__ ovf,
                   const int* __restrict__ novf,
                   float* __restrict__ out) {
    __shared__ float ldsO[16 * 132];   // root contribution tile, row stride 132

    const int tid  = threadIdx.x;
    const int wave = tid >> 6;
    const int lane = tid & 63;
    const int m    = lane & 15;
    const int quad = lane >> 4;
    const int nb   = blockIdx.x;       // nodes nb*16 .. nb*16+15

    // ---------- phase R: root MFMA on the block's 16-node x tile ----------
    {
        half8 br[2][4];
        float bb[2];
#pragma unroll
        for (int t = 0; t < 2; ++t) {
            const int nt = 2 * wave + t;
            const half_t* rp = Rt + (nt * 16 + m) * D + quad * 8;
#pragma unroll
            for (int kk = 0; kk < 4; ++kk)
                br[t][kk] = *(const half8*)(rp + kk * 32);
            bb[t] = bias[nt * 16 + m];
        }

        const float4* x4 = (const float4*)x;
        size_t ab = (size_t)(nb * 16 + m) * 32 + quad * 2;
        half8 a[4];
#pragma unroll
        for (int kk = 0; kk < 4; ++kk) {
            float4 v0 = x4[ab + kk * 8];
            float4 v1 = x4[ab + kk * 8 + 1];
            half8 h;
            h[0] = (half_t)v0.x; h[1] = (half_t)v0.y; h[2] = (half_t)v0.z; h[3] = (half_t)v0.w;
            h[4] = (half_t)v1.x; h[5] = (half_t)v1.y; h[6] = (half_t)v1.z; h[7] = (half_t)v1.w;
            a[kk] = h;
        }

        f32x4 accR[2];
#pragma unroll
        for (int t = 0; t < 2; ++t) accR[t] = (f32x4){0.f, 0.f, 0.f, 0.f};
#pragma unroll
        for (int t = 0; t < 2; ++t)
#pragma unroll
            for (int kk = 0; kk < 4; ++kk)
                accR[t] = __builtin_amdgcn_mfma_f32_16x16x32_f16(a[kk], br[t][kk], accR[t], 0, 0, 0);

#pragma unroll
        for (int t = 0; t < 2; ++t) {
            const int nt = 2 * wave + t;
#pragma unroll
            for (int r = 0; r < 4; ++r)
                ldsO[(quad * 4 + r) * 132 + nt * 16 + m] = accR[t][r] + bb[t];
        }
    }
    __syncthreads();

    // ---------- phase G: 4 nodes per wave ----------
    for (int i = 0; i < 4; ++i) {
        const int node = nb * 16 + wave * 4 + i;
        const int* bp = bucket + (size_t)node * PAD;

        int c_raw = cnt[node];
        int idx[8];
#pragma unroll
        for (int j = 0; j < 8; ++j)
            idx[j] = bp[quad * 8 + j];     // issues in parallel with cnt load

        int c = c_raw > PAD ? PAD : c_raw;
#pragma unroll
        for (int j = 0; j < 8; ++j)
            idx[j] = (quad * 8 + j < c) ? idx[j] : N_NODES;   // pad -> zero row

        half8 v[8];
#pragma unroll
        for (int j = 0; j < 8; ++j)
            v[j] = *(const half8*)(y + (size_t)idx[j] * D + m * 8);

        float acc[8];
#pragma unroll
        for (int t = 0; t < 8; ++t)
            acc[t] = (((float)v[0][t] + (float)v[1][t]) + ((float)v[2][t] + (float)v[3][t]))
                   + (((float)v[4][t] + (float)v[5][t]) + ((float)v[6][t] + (float)v[7][t]));

        if (c_raw > PAD) {               // rare: side-list scan, strided by group
            int n = *novf;
            for (int k = quad; k < n; k += 4) {
                if (ovf[2 * k + 1] == node) {
                    half8 w = *(const half8*)(y + (size_t)ovf[2 * k] * D + m * 8);
#pragma unroll
                    for (int t = 0; t < 8; ++t) acc[t] += (float)w[t];
                }
            }
        }

#pragma unroll
        for (int t = 0; t < 8; ++t) {
            acc[t] += __shfl_xor(acc[t], 16);
            acc[t] += __shfl_xor(acc[t], 32);
        }

        if (quad == 0) {
            const float* so = ldsO + (wave * 4 + i) * 132 + m * 8;
            float4 o0 = *(const float4*)(so);
            float4 o1 = *(const float4*)(so + 4);
            o0.x += acc[0]; o0.y += acc[1]; o0.z += acc[2]; o0.w += acc[3];
            o1.x += acc[4]; o1.y += acc[5]; o1.z += acc[6]; o1.w += acc[7];
            float4* op = (float4*)(out + (size_t)node * D + m * 8);
            op[0] = o0;
            op[1] = o1;
        }
    }
}

extern "C" void kernel_launch(void* const* d_in, const int* in_sizes, int n_in,
                              void* d_out, int out_size, void* d_ws, size_t ws_size,
                              hipStream_t stream) {
    const float* x     = (const float*)d_in[0];
    const int*   eidx  = (const int*)d_in[1];
    const float* bases = (const float*)d_in[2];
    const float* comp  = (const float*)d_in[3];
    const float* root  = (const float*)d_in[4];
    const float* bias  = (const float*)d_in[5];
    float* out = (float*)d_out;

    char* ws = (char*)d_ws;
    half_t* y      = (half_t*)ws;                      // 12,800,512 B (50001 rows, padded)
    half_t* Wt     = (half_t*)(ws + 12800512);         //     32,768 B
    half_t* Rt     = (half_t*)(ws + 12833280);         //     32,768 B
    int*    cnt    = (int*)   (ws + 12866048);         //    200,000 B
    int*    bucket = (int*)   (ws + 13066048);         //  6,400,000 B
    int*    novf   = (int*)   (ws + 19466048);         //         16 B
    int*    ovf    = (int*)   (ws + 19466064);         //  5,120,000 B (capacity == E)

    init_kernel<<<(N_NODES + 255) / 256, 256, 0, stream>>>(
        bases, comp, root, Wt, Rt, y, cnt, novf);
    fused_kernel<<<BUCKET_B + GEMM_B, 256, 0, stream>>>(
        x, Wt, eidx, y, cnt, bucket, ovf, novf);
    gather_kernel<<<NBLK_G, 256, 0, stream>>>(
        x, Rt, bias, cnt, bucket, y, ovf, novf, out);
}

// Round 9
// 153.482 us; speedup vs baseline: 1.0921x; 1.0921x over previous
//
#include <hip/hip_runtime.h>

#define N_NODES 50000
#define HALF    25000  // dst-space chunk boundary for the software pipeline
#define N_EDGES 640000
#define D 128          // D_IN == D_OUT
#define NB 8           // num bases
#define PAD 32         // bucket slots per dst (mean deg 12.8; overflow -> side list)
#define NSTRIP 3125    // 50000 / 16 row-strips

// k1 roles: 256 bucket blocks (proven optimum; contention-bound) + 768 gemm.
#define BUCKET_B 256
#define GEMM_B   768
#define GBLK_H   6250  // gather blocks per half (4 nodes/block, 25000 nodes)

typedef _Float16 half_t;
typedef __attribute__((ext_vector_type(8))) _Float16 half8;
typedef __attribute__((ext_vector_type(4))) float f32x4;

// ---- k0: zero counters + build Wt/Rt (fp16, transposed [n][k]) + zero y pad row ----
__global__ __launch_bounds__(256)
void init_kernel(const float* __restrict__ bases,
                 const float* __restrict__ comp,
                 const float* __restrict__ root,
                 half_t* __restrict__ Wt,
                 half_t* __restrict__ Rt,
                 half_t* __restrict__ y,
                 int* __restrict__ cnt,
                 int* __restrict__ novf) {
    int i = blockIdx.x * 256 + threadIdx.x;
    if (i == 0) *novf = 0;
    if (i < N_NODES) cnt[i] = 0;
    if (i < D) y[(size_t)N_NODES * D + i] = (half_t)0.f;   // zero row for gather padding
    if (i < D * D) {
        int ii = i >> 7, o = i & 127;
        float acc = 0.f;
#pragma unroll
        for (int b = 0; b < NB; ++b)
            acc += comp[b] * bases[((size_t)b * D + ii) * D + o];
        Wt[o * D + ii] = (half_t)acc;
        Rt[o * D + ii] = (half_t)root[i];
    }
}

// ---- k1 (fused): bucket pass A (dst < HALF) || full dual GEMM ----
// Bucket-A (~half the atomics) hides under the GEMM (y = x@W, out = x@root+bias).
__global__ __launch_bounds__(256, 4)
void fused_kernel(const float* __restrict__ x,
                  const half_t* __restrict__ Wt,   // [n][k]
                  const half_t* __restrict__ Rt,   // [n][k]
                  const float* __restrict__ bias,
                  const int* __restrict__ eidx,
                  half_t* __restrict__ y,
                  float* __restrict__ out,
                  int* __restrict__ cnt,
                  int* __restrict__ bucket,
                  int* __restrict__ ovf,
                  int* __restrict__ novf) {
    const int tid = threadIdx.x;

    if (blockIdx.x < BUCKET_B) {
        // ---------------- bucket role, pass A: dst < HALF ----------------
        int t = blockIdx.x * 256 + tid;
        for (int e = t; e < N_EDGES; e += BUCKET_B * 256) {
            int dst = eidx[N_EDGES + e];
            if (dst < HALF) {
                int src = eidx[e];
                int pos = atomicAdd(&cnt[dst], 1);
                if (pos < PAD) {
                    bucket[(size_t)dst * PAD + pos] = src;
                } else {        // P ~ 1e-6/node; capacity == E, never drops
                    int k = atomicAdd(novf, 1);
                    ovf[2 * k]     = src;
                    ovf[2 * k + 1] = dst;
                }
            }
        }
        return;
    }

    // ---------------- gemm role: y = x@W ; out = x@root + bias ----------------
    const int gb   = blockIdx.x - BUCKET_B;  // 0 .. GEMM_B-1
    const int wave = tid >> 6;
    const int lane = tid & 63;
    const int m    = lane & 15;
    const int quad = lane >> 4;
    const int q    = wave;                   // col quarter: nt = 2q, 2q+1

    // B fragments, loaded ONCE: B[k][n], n = lane&15, k = quad*8 + j
    half8 bw[2][4], br[2][4];
    float bb[2];
#pragma unroll
    for (int t = 0; t < 2; ++t) {
        const int nt = 2 * q + t;
        const half_t* wp = Wt + (nt * 16 + m) * D + quad * 8;
        const half_t* rp = Rt + (nt * 16 + m) * D + quad * 8;
#pragma unroll
        for (int kk = 0; kk < 4; ++kk) {
            bw[t][kk] = *(const half8*)(wp + kk * 32);
            br[t][kk] = *(const half8*)(rp + kk * 32);
        }
        bb[t] = bias[nt * 16 + m];
    }

    const float4* x4 = (const float4*)x;
    for (int s = gb; s < NSTRIP; s += GEMM_B) {
        // A fragment: A[m][k], row = s*16 + m, k = quad*8 + j
        size_t ab = (size_t)(s * 16 + m) * 32 + quad * 2;
        half8 a[4];
#pragma unroll
        for (int kk = 0; kk < 4; ++kk) {
            float4 v0 = x4[ab + kk * 8];
            float4 v1 = x4[ab + kk * 8 + 1];
            half8 h;
            h[0] = (half_t)v0.x; h[1] = (half_t)v0.y; h[2] = (half_t)v0.z; h[3] = (half_t)v0.w;
            h[4] = (half_t)v1.x; h[5] = (half_t)v1.y; h[6] = (half_t)v1.z; h[7] = (half_t)v1.w;
            a[kk] = h;
        }

        f32x4 accW[2], accR[2];
#pragma unroll
        for (int t = 0; t < 2; ++t) {
            accW[t] = (f32x4){0.f, 0.f, 0.f, 0.f};
            accR[t] = (f32x4){0.f, 0.f, 0.f, 0.f};
        }
#pragma unroll
        for (int t = 0; t < 2; ++t)
#pragma unroll
            for (int kk = 0; kk < 4; ++kk) {
                accW[t] = __builtin_amdgcn_mfma_f32_16x16x32_f16(a[kk], bw[t][kk], accW[t], 0, 0, 0);
                accR[t] = __builtin_amdgcn_mfma_f32_16x16x32_f16(a[kk], br[t][kk], accR[t], 0, 0, 0);
            }

        // C/D layout: col = lane&15, row = quad*4 + reg
#pragma unroll
        for (int t = 0; t < 2; ++t) {
            int col = (2 * q + t) * 16 + m;
#pragma unroll
            for (int r = 0; r < 4; ++r) {
                int row = s * 16 + quad * 4 + r;
                y[(size_t)row * D + col]   = (half_t)accW[t][r];
                out[(size_t)row * D + col] = accR[t][r] + bb[t];
            }
        }
    }
}

// ---- k2/k3 (pipe): optional bucket pass B (dst >= HALF) || gather half ----
// BKB > 0 (k2): blocks [0,BKB) bucket the second dst-half WHILE the remaining
// blocks gather the first node-half (whose bucket lists were finalized in k1).
// BKB == 0 (k3): pure gather of the second node-half.
// Gather: ONE WAVE PER NODE (proven R3 structure): group g = lane>>4 owns an
// edge-quarter (<= 8 since c <= PAD); q = lane&15 owns col block q*8; loads
// padded to the zeroed y row; shfl_xor(16,32) combine; g==0 does the RMW.
template<int BKB, int NODE0>
__global__ __launch_bounds__(256)
void pipe_kernel(const int* __restrict__ eidx,
                 const int* __restrict__ cnt,
                 const int* __restrict__ bucket,
                 const half_t* __restrict__ y,
                 int* __restrict__ ovf,
                 int* __restrict__ novf,
                 int* __restrict__ cnt_mut,
                 float* __restrict__ out) {
    const int tid = threadIdx.x;

    if (BKB > 0 && blockIdx.x < BKB) {
        // ---------------- bucket role, pass B: dst >= HALF ----------------
        int t = blockIdx.x * 256 + tid;
        int* bkt = (int*)bucket;
        for (int e = t; e < N_EDGES; e += BKB * 256) {
            int dst = eidx[N_EDGES + e];
            if (dst >= HALF) {
                int src = eidx[e];
                int pos = atomicAdd(&cnt_mut[dst], 1);
                if (pos < PAD) {
                    bkt[(size_t)dst * PAD + pos] = src;
                } else {
                    int k = atomicAdd(novf, 1);
                    ovf[2 * k]     = src;
                    ovf[2 * k + 1] = dst;
                }
            }
        }
        return;
    }

    // ---------------- gather role ----------------
    const int wave = tid >> 6;
    const int lane = tid & 63;
    const int g    = lane >> 4;
    const int q    = lane & 15;
    const int node = NODE0 + (blockIdx.x - BKB) * 4 + wave;

    int c_raw = cnt[node];
    int c = c_raw > PAD ? PAD : c_raw;
    const int* bp = bucket + (size_t)node * PAD;

    int base = (c * g) >> 2;
    int ng   = ((c * (g + 1)) >> 2) - base;   // 0..8

    int idx[8];
#pragma unroll
    for (int j = 0; j < 8; ++j)
        idx[j] = (j < ng) ? bp[base + j] : N_NODES;   // pad -> zero row

    half8 v[8];
#pragma unroll
    for (int j = 0; j < 8; ++j)
        v[j] = *(const half8*)(y + (size_t)idx[j] * D + q * 8);

    float acc[8];
#pragma unroll
    for (int t = 0; t < 8; ++t)
        acc[t] = (((float)v[0][t] + (float)v[1][t]) + ((float)v[2][t] + (float)v[3][t]))
               + (((float)v[4][t] + (float)v[5][t]) + ((float)v[6][t] + (float)v[7][t]));

    if (c_raw > PAD) {               // rare: side-list scan, strided by group
        int n = *novf;
        for (int k = g; k < n; k += 4) {
            if (ovf[2 * k + 1] == node) {
                half8 w = *(const half8*)(y + (size_t)ovf[2 * k] * D + q * 8);
#pragma unroll
                for (int t = 0; t < 8; ++t) acc[t] += (float)w[t];
            }
        }
    }

#pragma unroll
    for (int t = 0; t < 8; ++t) {
        acc[t] += __shfl_xor(acc[t], 16);
        acc[t] += __shfl_xor(acc[t], 32);
    }

    if (g == 0) {
        float4* op = (float4*)(out + (size_t)node * D + q * 8);
        float4 o0 = op[0], o1 = op[1];
        o0.x += acc[0]; o0.y += acc[1]; o0.z += acc[2]; o0.w += acc[3];
        o1.x += acc[4]; o1.y += acc[5]; o1.z += acc[6]; o1.w += acc[7];
        op[0] = o0; op[1] = o1;
    }
}

extern "C" void kernel_launch(void* const* d_in, const int* in_sizes, int n_in,
                              void* d_out, int out_size, void* d_ws, size_t ws_size,
                              hipStream_t stream) {
    const float* x     = (const float*)d_in[0];
    const int*   eidx  = (const int*)d_in[1];
    const float* bases = (const float*)d_in[2];
    const float* comp  = (const float*)d_in[3];
    const float* root  = (const float*)d_in[4];
    const float* bias  = (const float*)d_in[5];
    float* out = (float*)d_out;

    char* ws = (char*)d_ws;
    half_t* y      = (half_t*)ws;                      // 12,800,512 B (50001 rows, padded)
    half_t* Wt     = (half_t*)(ws + 12800512);         //     32,768 B
    half_t* Rt     = (half_t*)(ws + 12833280);         //     32,768 B
    int*    cnt    = (int*)   (ws + 12866048);         //    200,000 B
    int*    bucket = (int*)   (ws + 13066048);         //  6,400,000 B
    int*    novf   = (int*)   (ws + 19466048);         //         16 B
    int*    ovf    = (int*)   (ws + 19466064);         //  5,120,000 B (capacity == E)

    init_kernel<<<(N_NODES + 255) / 256, 256, 0, stream>>>(
        bases, comp, root, Wt, Rt, y, cnt, novf);
    // k1: bucket pass A (dst < HALF)  ||  full dual GEMM
    fused_kernel<<<BUCKET_B + GEMM_B, 256, 0, stream>>>(
        x, Wt, Rt, bias, eidx, y, out, cnt, bucket, ovf, novf);
    // k2: bucket pass B (dst >= HALF) ||  gather nodes [0, HALF)
    pipe_kernel<BUCKET_B, 0><<<BUCKET_B + GBLK_H, 256, 0, stream>>>(
        eidx, cnt, bucket, y, ovf, novf, cnt, out);
    // k3: gather nodes [HALF, N_NODES)
    pipe_kernel<0, HALF><<<GBLK_H, 256, 0, stream>>>(
        eidx, cnt, bucket, y, ovf, novf, cnt, out);
}